// Round 2
// baseline (1188.400 us; speedup 1.0000x reference)
//
#include <hip/hip_runtime.h>
#include <stdint.h>

#define NE    1600000
#define DIM   128
#define HID   64

// ---------------- JAX threefry2x32 core (bit-exact) ----------------
struct TF2 { uint32_t a, b; };

__host__ __device__ constexpr uint32_t rotl32(uint32_t x, int d) {
  return (x << d) | (x >> (32 - d));
}

__host__ __device__ constexpr TF2 threefry(uint32_t k0, uint32_t k1,
                                           uint32_t c0, uint32_t c1) {
  uint32_t ks[3] = { k0, k1, k0 ^ k1 ^ 0x1BD11BDAu };
  uint32_t x0 = c0 + ks[0], x1 = c1 + ks[1];
  const int rot[2][4] = { {13, 15, 26, 6}, {17, 29, 16, 24} };
  for (int i = 0; i < 5; ++i) {
    for (int r = 0; r < 4; ++r) {
      x0 += x1;
      x1 = rotl32(x1, rot[i & 1][r]);
      x1 ^= x0;
    }
    x0 += ks[(i + 1) % 3];
    x1 += ks[(i + 2) % 3] + (uint32_t)(i + 1);
  }
  return { x0, x1 };
}

// jax.random.key(42) -> key data (0, 42).
// jax_threefry_partitionable=True (default in modern JAX):
//   split (fold-like): child key j = full threefry output over counter
//   (hi, lo) = (0, j):  nk1 = tf(key, 0, 0), nk2 = tf(key, 0, 1).
constexpr TF2 SPA = threefry(0u, 42u, 0u, 0u);
constexpr TF2 SPB = threefry(0u, 42u, 0u, 1u);
constexpr uint32_t NK1_0 = SPA.a, NK1_1 = SPA.b;
constexpr uint32_t NK2_0 = SPB.a, NK2_1 = SPB.b;

// partitionable random_bits (32-bit): bits[i] = y0 ^ y1 of
// threefry(key, hi32(i), lo32(i));  i < 2^32 here so hi = 0.
__device__ inline float gumbel_elem(uint32_t k0, uint32_t k1, uint32_t i) {
  TF2 t = threefry(k0, k1, 0u, i);
  uint32_t bits = t.a ^ t.b;
  // jax._src.random._uniform: bitcast((bits>>9)|0x3f800000)-1; *(1-tiny)+tiny; max(tiny,.)
  float f = __uint_as_float((bits >> 9) | 0x3f800000u) - 1.0f;
  float u = fmaxf(1.1754943508222875e-38f, f + 1.1754943508222875e-38f);
  return -logf(-logf(u));
}

// ---------------- fused gather + MLP + gumbel-sigmoid ----------------
__global__ __launch_bounds__(256, 4)
void edge_prune_kernel(const float* __restrict__ node,
                       const int*   __restrict__ ei,
                       const float* __restrict__ W1,
                       const float* __restrict__ b1,
                       const float* __restrict__ W2,
                       const float* __restrict__ b2,
                       float*       __restrict__ out) {
  const int tid    = blockIdx.x * blockDim.x + threadIdx.x;
  const int stride = gridDim.x * blockDim.x;
  const float bias2 = b2[0];  // wave-uniform

  for (int e = tid; e < NE; e += stride) {
    const int r = ei[e];
    const int c = ei[NE + e];
    const float4* __restrict__ up = (const float4*)(node + (size_t)r * DIM);
    const float4* __restrict__ vp = (const float4*)(node + (size_t)c * DIM);

    float h[HID];
#pragma unroll
    for (int j = 0; j < HID; ++j) h[j] = b1[j];

#pragma unroll 1
    for (int dd = 0; dd < DIM / 4; ++dd) {
      const float4 xu = up[dd];
      const float4 xv = vp[dd];
      const float xs[8] = { xu.x, xu.y, xu.z, xu.w, xv.x, xv.y, xv.z, xv.w };
#pragma unroll
      for (int k = 0; k < 8; ++k) {
        const int drow = (k < 4) ? (dd * 4 + k) : (DIM + dd * 4 + (k - 4));
        const float4* __restrict__ wrow = (const float4*)(W1 + drow * HID);
        const float x = xs[k];
#pragma unroll
        for (int j4 = 0; j4 < HID / 4; ++j4) {
          const float4 w = wrow[j4];
          h[j4 * 4 + 0] = fmaf(x, w.x, h[j4 * 4 + 0]);
          h[j4 * 4 + 1] = fmaf(x, w.y, h[j4 * 4 + 1]);
          h[j4 * 4 + 2] = fmaf(x, w.z, h[j4 * 4 + 2]);
          h[j4 * 4 + 3] = fmaf(x, w.w, h[j4 * 4 + 3]);
        }
      }
    }

    float logit = bias2;
#pragma unroll
    for (int j = 0; j < HID; ++j) {
      logit = fmaf(fmaxf(h[j], 0.0f), W2[j], logit);
    }

    const float g1 = gumbel_elem(NK1_0, NK1_1, (uint32_t)e);
    const float g2 = gumbel_elem(NK2_0, NK2_1, (uint32_t)e);
    const float z  = logit + g1 - g2;            // TEMP = 1.0
    out[e] = 1.0f / (1.0f + expf(-z));
  }
}

extern "C" void kernel_launch(void* const* d_in, const int* in_sizes, int n_in,
                              void* d_out, int out_size, void* d_ws, size_t ws_size,
                              hipStream_t stream) {
  const float* node = (const float*)d_in[0];
  const int*   ei   = (const int*)  d_in[1];
  const float* W1   = (const float*)d_in[2];
  const float* b1   = (const float*)d_in[3];
  const float* W2   = (const float*)d_in[4];
  const float* b2   = (const float*)d_in[5];
  float* out = (float*)d_out;

  // 1024 WGs x 256 threads = 262144 threads; ~6.1 edges/thread grid-stride.
  edge_prune_kernel<<<dim3(1024), dim3(256), 0, stream>>>(node, ei, W1, b1, W2, b2, out);
}

// Round 3
// 134.602 us; speedup vs baseline: 8.8290x; 8.8290x over previous
//
#include <hip/hip_runtime.h>
#include <hip/hip_bf16.h>
#include <stdint.h>

#define N_NODES 50000
#define NE      1600000
#define DIM     128
#define HID     64

// ---------------- JAX threefry2x32 core (bit-exact) ----------------
struct TF2 { uint32_t a, b; };

__host__ __device__ constexpr uint32_t rotl32(uint32_t x, int d) {
  return (x << d) | (x >> (32 - d));
}

__host__ __device__ constexpr TF2 threefry(uint32_t k0, uint32_t k1,
                                           uint32_t c0, uint32_t c1) {
  uint32_t ks[3] = { k0, k1, k0 ^ k1 ^ 0x1BD11BDAu };
  uint32_t x0 = c0 + ks[0], x1 = c1 + ks[1];
  const int rot[2][4] = { {13, 15, 26, 6}, {17, 29, 16, 24} };
  for (int i = 0; i < 5; ++i) {
    for (int r = 0; r < 4; ++r) {
      x0 += x1;
      x1 = rotl32(x1, rot[i & 1][r]);
      x1 ^= x0;
    }
    x0 += ks[(i + 1) % 3];
    x1 += ks[(i + 2) % 3] + (uint32_t)(i + 1);
  }
  return { x0, x1 };
}

// jax_threefry_partitionable split: nk_j = full threefry(key, (0, j))
constexpr TF2 SPA = threefry(0u, 42u, 0u, 0u);
constexpr TF2 SPB = threefry(0u, 42u, 0u, 1u);
constexpr uint32_t NK1_0 = SPA.a, NK1_1 = SPA.b;
constexpr uint32_t NK2_0 = SPB.a, NK2_1 = SPB.b;

__device__ inline float gumbel_elem(uint32_t k0, uint32_t k1, uint32_t i) {
  TF2 t = threefry(k0, k1, 0u, i);
  uint32_t bits = t.a ^ t.b;
  float f = __uint_as_float((bits >> 9) | 0x3f800000u) - 1.0f;
  float u = fmaxf(1.1754943508222875e-38f, f + 1.1754943508222875e-38f);
  return -logf(-logf(u));
}

__device__ inline unsigned short f2bf_rne(float f) {
  uint32_t u = __float_as_uint(f);
  uint32_t r = (u + 0x7fffu + ((u >> 16) & 1u)) >> 16;
  return (unsigned short)r;
}

// ---------------- pass 1: per-node partial MLP ----------------
// A[v] = x_v @ W1[0:128]   + b1   (p == 0)
// B[v] = x_v @ W1[128:256]        (p == 1)
// p derived from blockIdx -> wave-uniform -> W1 loads scalarize to s_load.
#define NBLK_HALF 196  // ceil(50000/256)

__global__ __launch_bounds__(256, 2)
void node_half_kernel(const float* __restrict__ node,
                      const float* __restrict__ W1,
                      const float* __restrict__ b1,
                      unsigned short* __restrict__ A_tab,
                      unsigned short* __restrict__ B_tab) {
  const int p = (blockIdx.x >= NBLK_HALF);
  const int v = (blockIdx.x - (p ? NBLK_HALF : 0)) * blockDim.x + threadIdx.x;
  if (v >= N_NODES) return;

  const float4* __restrict__ xp = (const float4*)(node + (size_t)v * DIM);
  const float*  __restrict__ Wb = W1 + (size_t)p * DIM * HID;

  float acc[HID];
  if (p == 0) {
#pragma unroll
    for (int j = 0; j < HID; ++j) acc[j] = b1[j];
  } else {
#pragma unroll
    for (int j = 0; j < HID; ++j) acc[j] = 0.0f;
  }

#pragma unroll 2
  for (int dd = 0; dd < DIM / 4; ++dd) {
    const float4 x4 = xp[dd];
    const float xs[4] = { x4.x, x4.y, x4.z, x4.w };
#pragma unroll
    for (int k = 0; k < 4; ++k) {
      const float x = xs[k];
      const float4* __restrict__ wrow = (const float4*)(Wb + (size_t)(dd * 4 + k) * HID);
#pragma unroll
      for (int j4 = 0; j4 < HID / 4; ++j4) {
        const float4 w = wrow[j4];
        acc[4 * j4 + 0] = fmaf(x, w.x, acc[4 * j4 + 0]);
        acc[4 * j4 + 1] = fmaf(x, w.y, acc[4 * j4 + 1]);
        acc[4 * j4 + 2] = fmaf(x, w.z, acc[4 * j4 + 2]);
        acc[4 * j4 + 3] = fmaf(x, w.w, acc[4 * j4 + 3]);
      }
    }
  }

  unsigned short* dst = (p ? B_tab : A_tab) + (size_t)v * HID;
#pragma unroll
  for (int q = 0; q < HID / 8; ++q) {
    union { unsigned short us[8]; uint4 u4; } pk;
#pragma unroll
    for (int t = 0; t < 8; ++t) pk.us[t] = f2bf_rne(acc[q * 8 + t]);
    ((uint4*)dst)[q] = pk.u4;
  }
}

// ---------------- pass 2: per-edge gather-add-relu-dot + noise ----------------
__global__ __launch_bounds__(256, 4)
void edge_kernel(const int* __restrict__ ei,
                 const unsigned short* __restrict__ A_tab,
                 const unsigned short* __restrict__ B_tab,
                 const float* __restrict__ W2,
                 const float* __restrict__ b2,
                 float* __restrict__ out) {
  const int tid    = blockIdx.x * blockDim.x + threadIdx.x;
  const int stride = gridDim.x * blockDim.x;
  const float bias2 = b2[0];

  for (int e = tid; e < NE; e += stride) {
    const int r = ei[e];
    const int c = ei[NE + e];
    const uint4* __restrict__ ap = (const uint4*)(A_tab + (size_t)r * HID);
    const uint4* __restrict__ bp = (const uint4*)(B_tab + (size_t)c * HID);

    uint4 av[8], bv[8];
#pragma unroll
    for (int q = 0; q < 8; ++q) av[q] = ap[q];
#pragma unroll
    for (int q = 0; q < 8; ++q) bv[q] = bp[q];

    float logit = bias2;
#pragma unroll
    for (int q = 0; q < 8; ++q) {
      const uint32_t* au = (const uint32_t*)&av[q];
      const uint32_t* bu = (const uint32_t*)&bv[q];
#pragma unroll
      for (int t = 0; t < 4; ++t) {
        const float a0 = __uint_as_float(au[t] << 16);
        const float a1 = __uint_as_float(au[t] & 0xffff0000u);
        const float b0 = __uint_as_float(bu[t] << 16);
        const float b1v = __uint_as_float(bu[t] & 0xffff0000u);
        const int j = q * 8 + t * 2;
        logit = fmaf(fmaxf(a0 + b0, 0.0f),  W2[j],     logit);
        logit = fmaf(fmaxf(a1 + b1v, 0.0f), W2[j + 1], logit);
      }
    }

    const float g1 = gumbel_elem(NK1_0, NK1_1, (uint32_t)e);
    const float g2 = gumbel_elem(NK2_0, NK2_1, (uint32_t)e);
    const float z  = logit + g1 - g2;  // TEMP = 1.0
    out[e] = 1.0f / (1.0f + expf(-z));
  }
}

// ---------------- fallback (round-2 fused kernel) if ws too small ----------------
__global__ __launch_bounds__(256, 4)
void edge_prune_fallback(const float* __restrict__ node,
                         const int*   __restrict__ ei,
                         const float* __restrict__ W1,
                         const float* __restrict__ b1,
                         const float* __restrict__ W2,
                         const float* __restrict__ b2,
                         float*       __restrict__ out) {
  const int tid    = blockIdx.x * blockDim.x + threadIdx.x;
  const int stride = gridDim.x * blockDim.x;
  const float bias2 = b2[0];

  for (int e = tid; e < NE; e += stride) {
    const int r = ei[e];
    const int c = ei[NE + e];
    const float4* __restrict__ up = (const float4*)(node + (size_t)r * DIM);
    const float4* __restrict__ vp = (const float4*)(node + (size_t)c * DIM);

    float h[HID];
#pragma unroll
    for (int j = 0; j < HID; ++j) h[j] = b1[j];

#pragma unroll 1
    for (int dd = 0; dd < DIM / 4; ++dd) {
      const float4 xu = up[dd];
      const float4 xv = vp[dd];
      const float xs[8] = { xu.x, xu.y, xu.z, xu.w, xv.x, xv.y, xv.z, xv.w };
#pragma unroll
      for (int k = 0; k < 8; ++k) {
        const int drow = (k < 4) ? (dd * 4 + k) : (DIM + dd * 4 + (k - 4));
        const float4* __restrict__ wrow = (const float4*)(W1 + drow * HID);
        const float x = xs[k];
#pragma unroll
        for (int j4 = 0; j4 < HID / 4; ++j4) {
          const float4 w = wrow[j4];
          h[j4 * 4 + 0] = fmaf(x, w.x, h[j4 * 4 + 0]);
          h[j4 * 4 + 1] = fmaf(x, w.y, h[j4 * 4 + 1]);
          h[j4 * 4 + 2] = fmaf(x, w.z, h[j4 * 4 + 2]);
          h[j4 * 4 + 3] = fmaf(x, w.w, h[j4 * 4 + 3]);
        }
      }
    }

    float logit = bias2;
#pragma unroll
    for (int j = 0; j < HID; ++j) logit = fmaf(fmaxf(h[j], 0.0f), W2[j], logit);

    const float g1 = gumbel_elem(NK1_0, NK1_1, (uint32_t)e);
    const float g2 = gumbel_elem(NK2_0, NK2_1, (uint32_t)e);
    const float z  = logit + g1 - g2;
    out[e] = 1.0f / (1.0f + expf(-z));
  }
}

extern "C" void kernel_launch(void* const* d_in, const int* in_sizes, int n_in,
                              void* d_out, int out_size, void* d_ws, size_t ws_size,
                              hipStream_t stream) {
  const float* node = (const float*)d_in[0];
  const int*   ei   = (const int*)  d_in[1];
  const float* W1   = (const float*)d_in[2];
  const float* b1   = (const float*)d_in[3];
  const float* W2   = (const float*)d_in[4];
  const float* b2   = (const float*)d_in[5];
  float* out = (float*)d_out;

  const size_t tab_bytes = (size_t)N_NODES * HID * sizeof(unsigned short);  // 6.4 MB
  if (ws_size >= 2 * tab_bytes) {
    unsigned short* A_tab = (unsigned short*)d_ws;
    unsigned short* B_tab = A_tab + (size_t)N_NODES * HID;
    // pass 1: 392 blocks (196 for A-half, 196 for B-half), wave-uniform weight base
    node_half_kernel<<<dim3(2 * NBLK_HALF), dim3(256), 0, stream>>>(
        node, W1, b1, A_tab, B_tab);
    // pass 2: grid-stride over edges, ~3 edges/thread
    edge_kernel<<<dim3(2048), dim3(256), 0, stream>>>(ei, A_tab, B_tab, W2, b2, out);
  } else {
    edge_prune_fallback<<<dim3(1024), dim3(256), 0, stream>>>(
        node, ei, W1, b1, W2, b2, out);
  }
}